// Round 7
// baseline (835.928 us; speedup 1.0000x reference)
//
#include <hip/hip_runtime.h>
#include <hip/hip_bf16.h>

#define NROWS 128           // B*E rows
#define NCOLS 4096          // N
#define KVAL  64
#define NEGV  (-1e30f)
#define LOG2E 1.4426950408889634f
#define LN2   0.6931471805599453f

// ESP tables, j=0 column (identically 0) NOT stored: slot j-1 holds state j.
__device__ float g_suf[(size_t)NROWS * (NCOLS + 1) * 64];
__device__ float g_pre[(size_t)NROWS * (NCOLS + 1) * 64];
__device__ unsigned long long g_mask[(size_t)2 * NROWS * NCOLS];   // [e][m][t]

// wave-wide shift-up-by-1 via DPP wave_shr:1 (0x138); lane 0 -> 0.0f.
__device__ __forceinline__ float wave_shr1_zero(float x) {
    int r = __builtin_amdgcn_update_dpp(0, __float_as_int(x), 0x138, 0xF, 0xF, true);
    return __int_as_float(r);
}

// fast logaddexp: max(a,b) + ln2 * log2(1 + exp2(-|a-b|*log2e))
__device__ __forceinline__ float lae_fast(float a, float b) {
    float mx = fmaxf(a, b);
    float d  = fabsf(a - b);
    float e  = __builtin_amdgcn_exp2f(d * -LOG2E);
    float lg = __builtin_amdgcn_logf(1.0f + e);
    return fmaf(lg, LN2, mx);
}

// theta at (m, t) in original scores layout (64,4096,2): uniform -> s_load
__device__ __forceinline__ float th_at(const float* __restrict__ scores, int m, int t) {
    return scores[((size_t)(m >> 1) * NCOLS + (size_t)t) * 2 + (m & 1)];
}

// One wave = TWO independent chains (suffix + prefix of row m), interleaved
// for 2x ILP on the lae latency chain. Lane l = state j=l+1; state 0 == 0.
__global__ __launch_bounds__(64) void dp_kernel(const float* __restrict__ scores) {
    int m = blockIdx.x;              // 0..127
    int l = threadIdx.x;
    float* __restrict__ suf = g_suf + (size_t)m * (NCOLS + 1) * 64;
    float* __restrict__ pre = g_pre + (size_t)m * (NCOLS + 1) * 64;
    const float* __restrict__ srow = scores + (size_t)(m >> 1) * (NCOLS * 2) + (m & 1);

    suf[(size_t)NCOLS * 64 + l] = NEGV;      // S init row (t = N)
    pre[l] = NEGV;                           // P init row (t = 0)
    float ss = NEGV, sp = NEGV;
    #pragma unroll 8
    for (int t = 0; t < NCOLS; ++t) {
        int ts = NCOLS - 1 - t;
        float ths = srow[(size_t)ts * 2];    // uniform -> scalar load
        float thp = srow[(size_t)t * 2];
        float bs = wave_shr1_zero(ss) + ths; // chain A (suffix)
        ss = lae_fast(ss, bs);
        suf[(size_t)ts * 64 + l] = ss;
        float bp = wave_shr1_zero(sp) + thp; // chain B (prefix), independent
        sp = lae_fast(sp, bp);
        pre[(size_t)(t + 1) * 64 + l] = sp;
    }
}

// Fused mask-gen + marginals. Unit (m, t0): S rows t0..t0+64 in registers feed
// BOTH the 64 sampler-mask steps (bit-identical to the passing version) and
// the 64 marginal LSEs (P row loaded JIT per element).
__global__ __launch_bounds__(256) void mid_kernel(const float* __restrict__ scores,
                                                  const float* __restrict__ u,
                                                  float* __restrict__ out) {
    int l = threadIdx.x & 63;
    int wid = threadIdx.x >> 6;
    int unit = blockIdx.x * 4 + wid;         // 0..8191
    int m  = unit >> 6;
    int t0 = (unit & 63) << 6;
    const float* __restrict__ S = g_suf + (size_t)m * (NCOLS + 1) * 64;
    const float* __restrict__ P = g_pre + (size_t)m * (NCOLS + 1) * 64;
    const float* __restrict__ srow = scores + (size_t)(m >> 1) * (NCOLS * 2) + (m & 1);
    const float* __restrict__ u0 = u + (size_t)m * NCOLS;             // ens 0
    const float* __restrict__ u1 = u + (size_t)(NROWS + m) * NCOLS;   // ens 1

    float R[65];                             // S rows t0..t0+64, lane l = slot l
    #pragma unroll
    for (int j = 0; j <= 64; ++j) R[j] = S[(size_t)(t0 + j) * 64 + l];

    float den_full = P[(size_t)NCOLS * 64 + 63];   // log E_k(full row), uniform

    unsigned long long acc0 = 0, acc1 = 0;   // lane ss <- masks of step t0+ss
    float mres = 0.0f;                       // lane j  <- marg of element t0+j
    #pragma unroll
    for (int j = 0; j < 64; ++j) {
        int t = t0 + j;
        float tht = srow[(size_t)t * 2];     // uniform
        // ---- sampler mask (identical expression to passing round-6 kernel)
        float num = wave_shr1_zero(R[j + 1]);        // row t+1, slot l-1 (lane0->0)
        float den = R[j];                            // row t, slot l
        float p = __builtin_amdgcn_exp2f(((num + tht) - den) * LOG2E);
        unsigned long long b0 = __ballot(u0[t] < p);
        unsigned long long b1 = __ballot(u1[t] < p);
        acc0 = (l == j) ? b0 : acc0;
        acc1 = (l == j) ? b1 : acc1;
        // ---- marginal: v_l = P[i][slot l-1] + S[i+1][slot 62-l]
        float Qj = P[(size_t)t * 64 + l];            // P row i, slot l
        float vP = wave_shr1_zero(Qj);               // slot l-1, lane0 -> state0 = 0
        float vS = (l == 63) ? 0.0f : __shfl(R[j + 1], 62 - l);   // slot 62-l
        float v = vP + vS;
        float M = v;
        #pragma unroll
        for (int off = 32; off; off >>= 1) M = fmaxf(M, __shfl_xor(M, off));
        float sum = __builtin_amdgcn_exp2f((v - M) * LOG2E);
        #pragma unroll
        for (int off = 32; off; off >>= 1) sum += __shfl_xor(sum, off);
        float lse = fmaf(__builtin_amdgcn_logf(sum), LN2, M);
        float mg = __builtin_amdgcn_exp2f((tht + lse - den_full) * LOG2E);
        mres = (l == j) ? mg : mres;
    }
    g_mask[(size_t)m * NCOLS + t0 + l] = acc0;               // coalesced 512B
    g_mask[(size_t)(NROWS + m) * NCOLS + t0 + l] = acc1;
    size_t obase = (size_t)2 * 64 * NCOLS * 2;
    out[obase + ((size_t)(m >> 1) * NCOLS + (t0 + l)) * 2 + (m & 1)] = mres;
}

// ---- sampler scan: register-tiled masks + __shfl broadcast (no mem on chain) ----
__global__ __launch_bounds__(64) void scan_kernel(float* __restrict__ out) {
    int chain = blockIdx.x;              // 0..255
    int l = threadIdx.x;
    int tens = chain >> 7;
    int m = chain & (NROWS - 1);
    const unsigned long long* __restrict__ gm =
        g_mask + ((size_t)tens * NROWS + m) * NCOLS;
    float* __restrict__ orow = out + (((size_t)tens * 64 + (m >> 1)) * NCOLS) * 2 + (m & 1);

    int r = KVAL;
    unsigned long long tile = gm[l];                 // coalesced 512B tile
    for (int t0 = 0; t0 < NCOLS; t0 += 64) {
        unsigned long long next = (t0 + 64 < NCOLS) ? gm[t0 + 64 + l] : 0ULL;
        int myinc = 0;
        #pragma unroll
        for (int ss = 0; ss < 64; ++ss) {
            unsigned long long msk = __shfl(tile, ss);           // VGPR broadcast
            int inc = (r > 0) ? (int)((msk >> (r - 1)) & 1ULL) : 0;
            myinc = (ss == l) ? inc : myinc;
            r -= inc;
        }
        orow[(size_t)(t0 + l) * 2] = (float)myinc;
        tile = next;
    }
}

extern "C" void kernel_launch(void* const* d_in, const int* in_sizes, int n_in,
                              void* d_out, int out_size, void* d_ws, size_t ws_size,
                              hipStream_t stream) {
    const float* scores = (const float*)d_in[0];   // (64, 4096, 2) f32
    const float* u      = (const float*)d_in[1];   // (2, 128, 4096) f32
    float* out = (float*)d_out;

    dp_kernel<<<NROWS, 64, 0, stream>>>(scores);
    mid_kernel<<<2048, 256, 0, stream>>>(scores, u, out);
    scan_kernel<<<2 * NROWS, 64, 0, stream>>>(out);
}

// Round 9
// 467.889 us; speedup vs baseline: 1.7866x; 1.7866x over previous
//
#include <hip/hip_runtime.h>
#include <hip/hip_bf16.h>

#define NROWS 128           // B*E rows
#define NCOLS 4096          // N
#define KVAL  64
#define NEGV  (-1e30f)
#define LOG2E 1.4426950408889634f
#define LN2   0.6931471805599453f

// ESP tables, j=0 column (identically 0) NOT stored: slot j-1 holds state j.
__device__ float g_suf[(size_t)NROWS * (NCOLS + 1) * 64];
__device__ float g_pre[(size_t)NROWS * (NCOLS + 1) * 64];
__device__ float g_th [(size_t)NROWS * NCOLS];                     // theta: [m][t]
__device__ unsigned long long g_mask[(size_t)2 * NROWS * NCOLS];   // [e][m][t]

// wave-wide shift-up-by-1 via DPP wave_shr:1 (0x138); lane 0 -> 0.0f.
__device__ __forceinline__ float shr1z(float x) {
    int r = __builtin_amdgcn_update_dpp(0, __float_as_int(x), 0x138, 0xF, 0xF, true);
    return __int_as_float(r);
}
__device__ __forceinline__ float readlane_f(float v, int lane) {
    return __int_as_float(__builtin_amdgcn_readlane(__float_as_int(v), lane));
}
// fast logaddexp: max(a,b) + ln2 * log2(1 + exp2(-|a-b|*log2e))
// (bit-identical to rounds 3..7 passing table construction)
__device__ __forceinline__ float lae_fast(float a, float b) {
    float mx = fmaxf(a, b);
    float d  = fabsf(a - b);
    float e  = __builtin_amdgcn_exp2f(d * -LOG2E);
    return fmaf(__builtin_amdgcn_logf(1.0f + e), LN2, mx);
}

// DPP wave64 reductions (VALU pipe; result lands in lane 63).
// row_shr:1/2/4/8 inclusive prefix within rows of 16, then row_bcast:15 (rows
// 1,3) and row_bcast:31 (rows 2,3). Invalid/disabled lanes take `old`:
// 0 for sum, x for max -> identity.
__device__ __forceinline__ float dpp_max64(float x) {
#define MSTEP(ctrl, rmask) { int t_ = __builtin_amdgcn_update_dpp(__float_as_int(x), \
        __float_as_int(x), ctrl, rmask, 0xF, false); x = fmaxf(x, __int_as_float(t_)); }
    MSTEP(0x111, 0xF) MSTEP(0x112, 0xF) MSTEP(0x114, 0xF) MSTEP(0x118, 0xF)
    MSTEP(0x142, 0xA) MSTEP(0x143, 0xC)
#undef MSTEP
    return readlane_f(x, 63);
}
__device__ __forceinline__ float dpp_sum64(float x) {
#define SSTEP(ctrl, rmask) { int t_ = __builtin_amdgcn_update_dpp(0, \
        __float_as_int(x), ctrl, rmask, 0xF, false); x = x + __int_as_float(t_); }
    SSTEP(0x111, 0xF) SSTEP(0x112, 0xF) SSTEP(0x114, 0xF) SSTEP(0x118, 0xF)
    SSTEP(0x142, 0xA) SSTEP(0x143, 0xC)
#undef SSTEP
    return readlane_f(x, 63);
}

// scores (64,4096,2) -> g_th[m=2b+e][t]
__global__ void transpose_kernel(const float* __restrict__ scores) {
    int idx = blockIdx.x * blockDim.x + threadIdx.x;   // over 64*4096
    int b = idx >> 12, n = idx & (NCOLS - 1);
    float2 v = ((const float2*)scores)[idx];
    g_th[(size_t)(2 * b)     * NCOLS + n] = v.x;
    g_th[(size_t)(2 * b + 1) * NCOLS + n] = v.y;
}

// Pure DP, EXACT round-6 form (known-passing bits). One wave per chain;
// blocks [0,128): suffix (backward), [128,256): prefix (forward).
// Lane l = state j=l+1; state 0 is identically 0 (DPP zero-fill).
__global__ __launch_bounds__(64) void dp_kernel() {
    int blk = blockIdx.x;
    int l = threadIdx.x;
    bool suf = (blk < NROWS);
    int m = suf ? blk : (blk - NROWS);
    float* __restrict__ tab = (suf ? g_suf : g_pre) + (size_t)m * (NCOLS + 1) * 64;
    const float* __restrict__ th = g_th + (size_t)m * NCOLS;

    tab[(size_t)(suf ? NCOLS : 0) * 64 + l] = NEGV;    // init state row
    float s = NEGV;
    if (suf) {
        #pragma unroll 8
        for (int tt = 0; tt < NCOLS; ++tt) {
            int t = NCOLS - 1 - tt;
            float b = shr1z(s) + th[t];                // th[t] uniform -> s_load
            s = lae_fast(s, b);
            tab[(size_t)t * 64 + l] = s;
        }
    } else {
        #pragma unroll 8
        for (int t = 0; t < NCOLS; ++t) {
            float b = shr1z(s) + th[t];
            s = lae_fast(s, b);
            tab[(size_t)(t + 1) * 64 + l] = s;
        }
    }
}

// Sampler ballot masks (round-6 semantics, bit-identical). One wave per (m,t0).
__global__ __launch_bounds__(256) void mask_kernel(const float* __restrict__ u) {
    int l = threadIdx.x & 63;
    int wid = threadIdx.x >> 6;
    int unit = blockIdx.x * 4 + wid;         // 0..8191
    int m  = unit >> 6;
    int t0 = (unit & 63) << 6;
    const float* __restrict__ S = g_suf + (size_t)m * (NCOLS + 1) * 64;
    const float* __restrict__ trow = g_th + (size_t)m * NCOLS;
    const float* __restrict__ u0 = u + (size_t)m * NCOLS;             // ens 0
    const float* __restrict__ u1 = u + (size_t)(NROWS + m) * NCOLS;   // ens 1

    float R[65];                             // S rows t0..t0+64, lane l = slot l
    #pragma unroll
    for (int j = 0; j <= 64; ++j) R[j] = S[(size_t)(t0 + j) * 64 + l];

    unsigned long long acc0 = 0, acc1 = 0;   // lane ss <- masks of step t0+ss
    #pragma unroll
    for (int ss = 0; ss < 64; ++ss) {
        int t = t0 + ss;
        float num = shr1z(R[ss + 1]);        // row t+1, state l (lane0 -> 0)
        float den = R[ss];                   // row t, state l+1
        float p = __builtin_amdgcn_exp2f(((num + trow[t]) - den) * LOG2E);
        unsigned long long b0 = __ballot(u0[t] < p);
        unsigned long long b1 = __ballot(u1[t] < p);
        acc0 = (l == ss) ? b0 : acc0;
        acc1 = (l == ss) ? b1 : acc1;
    }
    g_mask[(size_t)m * NCOLS + t0 + l] = acc0;               // coalesced 512B
    g_mask[(size_t)(NROWS + m) * NCOLS + t0 + l] = acc1;
}

// Marginals: one wave per 64-element group; DPP reductions (VALU pipe, no DS
// butterfly). v_a = P[i][a] + S[i+1][63-a]; slot map: P a-1 (a=0 -> 0),
// S 62-a (a=63 -> 0). Output 1 only (2e-2 tolerance).
__global__ __launch_bounds__(256) void marg_kernel(float* __restrict__ out) {
    int l = threadIdx.x & 63;
    int wid = threadIdx.x >> 6;
    int unit = blockIdx.x * 4 + wid;         // 0..8191
    int m  = unit >> 6;
    int t0 = (unit & 63) << 6;
    size_t rowbase = (size_t)m * (NCOLS + 1) * 64;
    const float* __restrict__ P = g_pre + rowbase;
    const float* __restrict__ S = g_suf + rowbase;
    const float* __restrict__ trow = g_th + (size_t)m * NCOLS;
    float den_full = P[(size_t)NCOLS * 64 + 63];     // log E_k(full row), uniform

    float mres = 0.0f;                       // lane j <- marg of element t0+j
    #pragma unroll 4
    for (int j = 0; j < 64; ++j) {
        int i = t0 + j;
        float vP = (l == 0)  ? 0.0f : P[(size_t)i * 64 + (l - 1)];        // state l
        float vS = (l == 63) ? 0.0f : S[(size_t)(i + 1) * 64 + (62 - l)]; // state 63-l
        float v = vP + vS;
        float M = dpp_max64(v);
        float sum = dpp_sum64(__builtin_amdgcn_exp2f((v - M) * LOG2E));
        float lse = fmaf(__builtin_amdgcn_logf(sum), LN2, M);
        float mg = __builtin_amdgcn_exp2f((trow[i] + lse - den_full) * LOG2E);
        mres = (l == j) ? mg : mres;
    }
    size_t obase = (size_t)2 * 64 * NCOLS * 2;
    out[obase + ((size_t)(m >> 1) * NCOLS + (t0 + l)) * 2 + (m & 1)] = mres;
}

// Sampler scan: register-tiled masks + __shfl broadcast (no mem on chain).
__global__ __launch_bounds__(64) void scan_kernel(float* __restrict__ out) {
    int chain = blockIdx.x;              // 0..255
    int l = threadIdx.x;
    int tens = chain >> 7;
    int m = chain & (NROWS - 1);
    const unsigned long long* __restrict__ gm =
        g_mask + ((size_t)tens * NROWS + m) * NCOLS;
    float* __restrict__ orow = out + (((size_t)tens * 64 + (m >> 1)) * NCOLS) * 2 + (m & 1);

    int r = KVAL;
    unsigned long long tile = gm[l];                 // coalesced 512B tile
    for (int t0 = 0; t0 < NCOLS; t0 += 64) {
        unsigned long long next = (t0 + 64 < NCOLS) ? gm[t0 + 64 + l] : 0ULL;
        int myinc = 0;
        #pragma unroll
        for (int ss = 0; ss < 64; ++ss) {
            unsigned long long msk = __shfl(tile, ss);           // VGPR broadcast
            int inc = (r > 0) ? (int)((msk >> (r - 1)) & 1ULL) : 0;
            myinc = (ss == l) ? inc : myinc;
            r -= inc;
        }
        orow[(size_t)(t0 + l) * 2] = (float)myinc;
        tile = next;
    }
}

extern "C" void kernel_launch(void* const* d_in, const int* in_sizes, int n_in,
                              void* d_out, int out_size, void* d_ws, size_t ws_size,
                              hipStream_t stream) {
    const float* scores = (const float*)d_in[0];   // (64, 4096, 2) f32
    const float* u      = (const float*)d_in[1];   // (2, 128, 4096) f32
    float* out = (float*)d_out;

    transpose_kernel<<<(64 * NCOLS) / 256, 256, 0, stream>>>(scores);
    dp_kernel<<<2 * NROWS, 64, 0, stream>>>();
    mask_kernel<<<2048, 256, 0, stream>>>(u);
    marg_kernel<<<2048, 256, 0, stream>>>(out);
    scan_kernel<<<2 * NROWS, 64, 0, stream>>>(out);
}